// Round 1
// baseline (328.262 us; speedup 1.0000x reference)
//
#include <hip/hip_runtime.h>

#define T_TOK 2048
#define HID   2048
#define NH    16
#define NKV   2
#define HD    128
#define QDIM  (NH * HD)                 // 2048
#define KVDIM (NKV * HD)                // 256
#define QKVDIM (QDIM + 2 * KVDIM)       // 2560

typedef float          f32x4  __attribute__((ext_vector_type(4)));
typedef unsigned short u16x8  __attribute__((ext_vector_type(8)));
typedef __bf16         bf16x8 __attribute__((ext_vector_type(8)));

__device__ __forceinline__ unsigned short f2bf(float f) {
    unsigned int u = __builtin_bit_cast(unsigned int, f);
    u += 0x7fffu + ((u >> 16) & 1u);   // round-to-nearest-even
    return (unsigned short)(u >> 16);
}

__device__ __forceinline__ f32x4 mfma16(u16x8 a, u16x8 b, f32x4 c) {
    return __builtin_amdgcn_mfma_f32_16x16x32_bf16(
        __builtin_bit_cast(bf16x8, a), __builtin_bit_cast(bf16x8, b), c, 0, 0, 0);
}

// ---------------------------------------------------------------------------
// K1: qkv = hidden @ [Wq;Wk;Wv]^T   (fp32 in, fp32 out, bf16 MFMA internally)
// 64x64 tile, BK=32, 4 waves (2x2), each wave 32x32 = 2x2 MFMA fragments.
// ---------------------------------------------------------------------------
__global__ __launch_bounds__(256) void qkv_gemm(
    const float* __restrict__ hidden,
    const float* __restrict__ Wq,
    const float* __restrict__ Wk,
    const float* __restrict__ Wv,
    float* __restrict__ qkv)
{
    __shared__ alignas(16) unsigned short As[64][40];  // +8 pad: ~2-way banks
    __shared__ alignas(16) unsigned short Bs[64][40];

    const int tid  = threadIdx.x;
    const int lane = tid & 63;
    const int w    = tid >> 6;
    const int lg   = lane >> 4, lc = lane & 15;
    const int mb   = blockIdx.y, nb = blockIdx.x;
    const int m0   = mb * 64, n0 = nb * 64;

    // weight source select (tile-uniform: 2048 and 2304 are multiples of 64)
    const float* Wrow; int nloc;
    if (n0 < QDIM)              { Wrow = Wq; nloc = n0; }
    else if (n0 < QDIM + KVDIM) { Wrow = Wk; nloc = n0 - QDIM; }
    else                        { Wrow = Wv; nloc = n0 - QDIM - KVDIM; }

    const int srow = tid >> 2;           // 0..63
    const int scol = (tid & 3) * 8;      // 0,8,16,24

    const int wr = (w >> 1) * 32, wc = (w & 1) * 32;
    f32x4 acc[2][2] = {};

    for (int kb = 0; kb < HID; kb += 32) {
        __syncthreads();
        {   // stage A tile (fp32 -> bf16)
            const float* s = &hidden[(m0 + srow) * HID + kb + scol];
            float4 a0 = *reinterpret_cast<const float4*>(s);
            float4 a1 = *reinterpret_cast<const float4*>(s + 4);
            unsigned short* d = &As[srow][scol];
            d[0]=f2bf(a0.x); d[1]=f2bf(a0.y); d[2]=f2bf(a0.z); d[3]=f2bf(a0.w);
            d[4]=f2bf(a1.x); d[5]=f2bf(a1.y); d[6]=f2bf(a1.z); d[7]=f2bf(a1.w);
        }
        {   // stage B tile (weights, [n][k] k-contiguous)
            const float* s = &Wrow[(nloc + srow) * HID + kb + scol];
            float4 b0 = *reinterpret_cast<const float4*>(s);
            float4 b1 = *reinterpret_cast<const float4*>(s + 4);
            unsigned short* d = &Bs[srow][scol];
            d[0]=f2bf(b0.x); d[1]=f2bf(b0.y); d[2]=f2bf(b0.z); d[3]=f2bf(b0.w);
            d[4]=f2bf(b1.x); d[5]=f2bf(b1.y); d[6]=f2bf(b1.z); d[7]=f2bf(b1.w);
        }
        __syncthreads();

        u16x8 af0 = *reinterpret_cast<const u16x8*>(&As[wr + lc][lg * 8]);
        u16x8 af1 = *reinterpret_cast<const u16x8*>(&As[wr + 16 + lc][lg * 8]);
        u16x8 bf0 = *reinterpret_cast<const u16x8*>(&Bs[wc + lc][lg * 8]);
        u16x8 bf1 = *reinterpret_cast<const u16x8*>(&Bs[wc + 16 + lc][lg * 8]);
        acc[0][0] = mfma16(af0, bf0, acc[0][0]);
        acc[0][1] = mfma16(af0, bf1, acc[0][1]);
        acc[1][0] = mfma16(af1, bf0, acc[1][0]);
        acc[1][1] = mfma16(af1, bf1, acc[1][1]);
    }

    #pragma unroll
    for (int mi = 0; mi < 2; mi++)
        #pragma unroll
        for (int ni = 0; ni < 2; ni++)
            #pragma unroll
            for (int j = 0; j < 4; j++)
                qkv[(m0 + wr + mi * 16 + lg * 4 + j) * QKVDIM
                    + n0 + wc + ni * 16 + lc] = acc[mi][ni][j];
}

// ---------------------------------------------------------------------------
// K2: fp32 RoPE on q/k, emit bf16 q_rope/k_rope/v. One block per token.
// ---------------------------------------------------------------------------
__global__ __launch_bounds__(256) void rope_kernel(
    const float* __restrict__ qkv,
    const int* __restrict__ positions,
    unsigned short* __restrict__ qr,
    unsigned short* __restrict__ kr,
    unsigned short* __restrict__ vr)
{
    const int t   = blockIdx.x;
    const int tid = threadIdx.x;
    __shared__ float cosv[64], sinv[64];

    if (tid < 64) {
        // inv_freq[j] = 10000^(-j/64) = exp(-j * ln(10000)/64)
        float invf = expf(-(float)tid * 0.14391156831212787f);
        float f = (float)positions[t] * invf;
        cosv[tid] = cosf(f);
        sinv[tid] = sinf(f);
    }
    __syncthreads();

    const float* row = qkv + (size_t)t * QKVDIM;

    // q: 16 heads x 64 rotation pairs
    for (int i = tid; i < NH * 64; i += 256) {
        int hh = i >> 6, j = i & 63;
        float x1 = row[hh * HD + j];
        float x2 = row[hh * HD + j + 64];
        float c = cosv[j], s = sinv[j];
        qr[(size_t)t * QDIM + hh * HD + j]      = f2bf(x1 * c - x2 * s);
        qr[(size_t)t * QDIM + hh * HD + j + 64] = f2bf(x2 * c + x1 * s);
    }
    // k: 2 heads x 64 pairs
    if (tid < NKV * 64) {
        int hh = tid >> 6, j = tid & 63;
        float x1 = row[QDIM + hh * HD + j];
        float x2 = row[QDIM + hh * HD + j + 64];
        float c = cosv[j], s = sinv[j];
        kr[(size_t)t * KVDIM + hh * HD + j]      = f2bf(x1 * c - x2 * s);
        kr[(size_t)t * KVDIM + hh * HD + j + 64] = f2bf(x2 * c + x1 * s);
    }
    // v: straight convert
    for (int i = tid; i < KVDIM; i += 256)
        vr[(size_t)t * KVDIM + i] = f2bf(row[QDIM + KVDIM + i]);
}

// ---------------------------------------------------------------------------
// K3: causal GQA flash attention. Block = (head, 64-q-row tile), 4 waves,
// each wave owns 16 q rows independently (no cross-wave sync; private LDS P).
// ---------------------------------------------------------------------------
__global__ __launch_bounds__(256) void attn_kernel(
    const unsigned short* __restrict__ q,   // bf16 [T][NH*HD]
    const unsigned short* __restrict__ k,   // bf16 [T][NKV*HD]
    const unsigned short* __restrict__ v,   // bf16 [T][NKV*HD]
    unsigned short* __restrict__ o)         // bf16 [T][NH*HD]
{
    __shared__ alignas(16) unsigned short P[4][16][40];  // per-wave, padded

    const int tid  = threadIdx.x;
    const int lane = tid & 63;
    const int w    = tid >> 6;
    const int lg   = lane >> 4, lc = lane & 15;
    const int h    = blockIdx.x >> 5;     // 16 heads
    const int qt   = blockIdx.x & 31;     // 32 q-tiles of 64
    const int q0   = qt * 64 + w * 16;
    const int hk   = h >> 3;              // GQA group = 8
    const float scale = 0.08838834764831845f;  // 128^-0.5

    u16x8 qf[4];
    #pragma unroll
    for (int dc = 0; dc < 4; dc++)
        qf[dc] = *reinterpret_cast<const u16x8*>(
            &q[(size_t)(q0 + lc) * QDIM + h * HD + dc * 32 + lg * 8]);

    float m[4], ell[4];
    #pragma unroll
    for (int j = 0; j < 4; j++) { m[j] = -1e30f; ell[j] = 0.f; }
    f32x4 oacc[8] = {};

    const int kend = q0 + 16;             // keys <= max q row in this wave
    for (int kb = 0; kb < kend; kb += 32) {
        float sc[2][4];
        #pragma unroll
        for (int c2 = 0; c2 < 2; c2++) {
            const int kc = kb + c2 * 16;
            f32x4 s = {0.f, 0.f, 0.f, 0.f};
            #pragma unroll
            for (int dc = 0; dc < 4; dc++) {
                u16x8 kf = *reinterpret_cast<const u16x8*>(
                    &k[(size_t)(kc + lc) * KVDIM + hk * HD + dc * 32 + lg * 8]);
                s = mfma16(qf[dc], kf, s);
            }
            #pragma unroll
            for (int j = 0; j < 4; j++) {
                const int qrow = q0 + lg * 4 + j;
                const int krow = kc + lc;
                sc[c2][j] = (krow <= qrow) ? s[j] * scale : -1e30f;
            }
        }
        // online softmax: row max over 16 keys/lane-group x 2 subtiles
        float alpha[4];
        #pragma unroll
        for (int j = 0; j < 4; j++) {
            float t = fmaxf(sc[0][j], sc[1][j]);
            #pragma unroll
            for (int off = 8; off >= 1; off >>= 1)
                t = fmaxf(t, __shfl_xor(t, off));
            float mn = fmaxf(m[j], t);
            alpha[j] = __expf(m[j] - mn);
            m[j] = mn;
        }
        float rs[4] = {0.f, 0.f, 0.f, 0.f};
        #pragma unroll
        for (int c2 = 0; c2 < 2; c2++)
            #pragma unroll
            for (int j = 0; j < 4; j++) {
                float p = __expf(sc[c2][j] - m[j]);
                rs[j] += p;
                P[w][lg * 4 + j][c2 * 16 + lc] = f2bf(p);
            }
        #pragma unroll
        for (int j = 0; j < 4; j++) {
            float t = rs[j];
            #pragma unroll
            for (int off = 8; off >= 1; off >>= 1)
                t += __shfl_xor(t, off);
            ell[j] = ell[j] * alpha[j] + t;
        }
        #pragma unroll
        for (int nt = 0; nt < 8; nt++)
            #pragma unroll
            for (int j = 0; j < 4; j++)
                oacc[nt][j] *= alpha[j];

        // per-wave LDS write->read: drain LDS queue, pin schedule (rule #18)
        asm volatile("s_waitcnt lgkmcnt(0)" ::: "memory");
        __builtin_amdgcn_sched_barrier(0);

        u16x8 pf = *reinterpret_cast<const u16x8*>(&P[w][lc][lg * 8]);

        #pragma unroll
        for (int nt = 0; nt < 8; nt++) {
            u16x8 vf;
            #pragma unroll
            for (int e = 0; e < 8; e++)
                vf[e] = v[(size_t)(kb + lg * 8 + e) * KVDIM + hk * HD + nt * 16 + lc];
            oacc[nt] = mfma16(pf, vf, oacc[nt]);
        }
    }

    #pragma unroll
    for (int nt = 0; nt < 8; nt++)
        #pragma unroll
        for (int j = 0; j < 4; j++) {
            float val = oacc[nt][j] / ell[j];
            o[(size_t)(q0 + lg * 4 + j) * QDIM + h * HD + nt * 16 + lc] = f2bf(val);
        }
}

// ---------------------------------------------------------------------------
// K4: out = attn(bf16) @ Wo^T (fp32 weights -> bf16), fp32 output.
// ---------------------------------------------------------------------------
__global__ __launch_bounds__(256) void out_gemm(
    const unsigned short* __restrict__ attn,  // bf16 [T][QDIM]
    const float* __restrict__ Wo,             // [HID][QDIM]
    float* __restrict__ out)                  // [T][HID]
{
    __shared__ alignas(16) unsigned short As[64][40];
    __shared__ alignas(16) unsigned short Bs[64][40];

    const int tid  = threadIdx.x;
    const int lane = tid & 63;
    const int w    = tid >> 6;
    const int lg   = lane >> 4, lc = lane & 15;
    const int mb   = blockIdx.y, nb = blockIdx.x;
    const int m0   = mb * 64, n0 = nb * 64;

    const int srow = tid >> 2;
    const int scol = (tid & 3) * 8;

    const int wr = (w >> 1) * 32, wc = (w & 1) * 32;
    f32x4 acc[2][2] = {};

    for (int kb = 0; kb < QDIM; kb += 32) {
        __syncthreads();
        {   // A already bf16: direct 16B copy
            u16x8 a = *reinterpret_cast<const u16x8*>(
                &attn[(size_t)(m0 + srow) * QDIM + kb + scol]);
            *reinterpret_cast<u16x8*>(&As[srow][scol]) = a;
        }
        {   // B fp32 -> bf16
            const float* s = &Wo[(size_t)(n0 + srow) * QDIM + kb + scol];
            float4 b0 = *reinterpret_cast<const float4*>(s);
            float4 b1 = *reinterpret_cast<const float4*>(s + 4);
            unsigned short* d = &Bs[srow][scol];
            d[0]=f2bf(b0.x); d[1]=f2bf(b0.y); d[2]=f2bf(b0.z); d[3]=f2bf(b0.w);
            d[4]=f2bf(b1.x); d[5]=f2bf(b1.y); d[6]=f2bf(b1.z); d[7]=f2bf(b1.w);
        }
        __syncthreads();

        u16x8 af0 = *reinterpret_cast<const u16x8*>(&As[wr + lc][lg * 8]);
        u16x8 af1 = *reinterpret_cast<const u16x8*>(&As[wr + 16 + lc][lg * 8]);
        u16x8 bf0 = *reinterpret_cast<const u16x8*>(&Bs[wc + lc][lg * 8]);
        u16x8 bf1 = *reinterpret_cast<const u16x8*>(&Bs[wc + 16 + lc][lg * 8]);
        acc[0][0] = mfma16(af0, bf0, acc[0][0]);
        acc[0][1] = mfma16(af0, bf1, acc[0][1]);
        acc[1][0] = mfma16(af1, bf0, acc[1][0]);
        acc[1][1] = mfma16(af1, bf1, acc[1][1]);
    }

    #pragma unroll
    for (int mi = 0; mi < 2; mi++)
        #pragma unroll
        for (int ni = 0; ni < 2; ni++)
            #pragma unroll
            for (int j = 0; j < 4; j++)
                out[(size_t)(m0 + wr + mi * 16 + lg * 4 + j) * HID
                    + n0 + wc + ni * 16 + lc] = acc[mi][ni][j];
}

// ---------------------------------------------------------------------------
extern "C" void kernel_launch(void* const* d_in, const int* in_sizes, int n_in,
                              void* d_out, int out_size, void* d_ws, size_t ws_size,
                              hipStream_t stream) {
    const float* hidden    = (const float*)d_in[0];
    const int*   positions = (const int*)d_in[1];
    const float* Wq        = (const float*)d_in[2];
    const float* Wk        = (const float*)d_in[3];
    const float* Wv        = (const float*)d_in[4];
    const float* Wo        = (const float*)d_in[5];
    float*       out       = (float*)d_out;

    char* ws = (char*)d_ws;
    // workspace layout (all 256B-aligned offsets), total ~39.8 MB
    float*          qkv = (float*)(ws);                                // 2048*2560*4 = 20971520
    unsigned short* qr  = (unsigned short*)(ws + 20971520);            // 2048*2048*2 =  8388608
    unsigned short* kr  = (unsigned short*)(ws + 20971520 + 8388608);  // 2048*256*2  =  1048576
    unsigned short* vr  = (unsigned short*)(ws + 20971520 + 9437184);  // 2048*256*2  =  1048576
    unsigned short* att = (unsigned short*)(ws + 20971520 + 10485760); // 2048*2048*2 =  8388608

    qkv_gemm<<<dim3(QKVDIM / 64, T_TOK / 64), 256, 0, stream>>>(hidden, Wq, Wk, Wv, qkv);
    rope_kernel<<<T_TOK, 256, 0, stream>>>(qkv, positions, qr, kr, vr);
    attn_kernel<<<NH * (T_TOK / 64), 256, 0, stream>>>(qr, kr, vr, att);
    out_gemm<<<dim3(HID / 64, T_TOK / 64), 256, 0, stream>>>(att, Wo, out);
}